// Round 13
// baseline (224.896 us; speedup 1.0000x reference)
//
#include <hip/hip_runtime.h>

#define HID 1024
#define SEQ 2048
#define NB 4
#define BS 8192  // NB*SEQ

typedef __attribute__((ext_vector_type(8))) short short8;
typedef __attribute__((ext_vector_type(8))) unsigned short ushort8;
typedef __attribute__((ext_vector_type(4))) float f32x4;

__device__ __forceinline__ float bf2f(unsigned short u) {
  unsigned int x = ((unsigned int)u) << 16;
  return __builtin_bit_cast(float, x);
}
__device__ __forceinline__ unsigned short f2bf(float f) {
  unsigned int x = __builtin_bit_cast(unsigned int, f);
  x = x + 0x7fffu + ((x >> 16) & 1u);
  return (unsigned short)(x >> 16);
}

#define GLOAD16(g, l)                                                          \
  __builtin_amdgcn_global_load_lds(                                            \
      (const __attribute__((address_space(1))) unsigned int*)(g),              \
      (__attribute__((address_space(3))) unsigned int*)(l), 16, 0, 0)

template <int N>
__device__ __forceinline__ void vmwait() {
  asm volatile("s_waitcnt vmcnt(%0)" ::"i"(N) : "memory");
}

// ---------------- fp32 -> bf16 cast, 8 elems/thread ----------------
__global__ void cast_f32_to_bf16(const float* __restrict__ in,
                                 unsigned short* __restrict__ out, int n) {
  int i = (blockIdx.x * 256 + threadIdx.x) * 8;
  if (i >= n) return;
  f32x4 a = *(const f32x4*)(in + i);
  f32x4 b = *(const f32x4*)(in + i + 4);
  ushort8 o;
  o[0] = f2bf(a[0]); o[1] = f2bf(a[1]); o[2] = f2bf(a[2]); o[3] = f2bf(a[3]);
  o[4] = f2bf(b[0]); o[5] = f2bf(b[1]); o[6] = f2bf(b[2]); o[7] = f2bf(b[3]);
  *(ushort8*)(out + i) = o;
}

// ------------- 1024x1024 fp32 -> bf16 transposed cast -------------
__global__ __launch_bounds__(256) void transpose_cast(
    const float* __restrict__ in, unsigned short* __restrict__ out) {
  __shared__ float t[32][33];
  const int bx = blockIdx.x * 32, by = blockIdx.y * 32;
  const int tx = threadIdx.x & 31, ty = threadIdx.x >> 5;  // 32 x 8
#pragma unroll
  for (int i = 0; i < 4; ++i)
    t[ty + i * 8][tx] = in[(by + ty + i * 8) * 1024 + bx + tx];
  __syncthreads();
#pragma unroll
  for (int i = 0; i < 4; ++i)
    out[(bx + ty + i * 8) * 1024 + by + tx] = f2bf(t[tx][ty + i * 8]);
}

// ------------- b'[h] = bo[h] + sum_k Wo[h,k] * bv[k] -------------
__global__ __launch_bounds__(256) void bias_fuse(const float* __restrict__ Wo,
                                                 const float* __restrict__ bv,
                                                 const float* __restrict__ bo,
                                                 float* __restrict__ bp) {
  const int row = blockIdx.x * 4 + (threadIdx.x >> 6);
  const int lane = threadIdx.x & 63;
  float s = 0.f;
  for (int k = lane; k < 1024; k += 64) s += Wo[row * 1024 + k] * bv[k];
#pragma unroll
  for (int off = 32; off >= 1; off >>= 1) s += __shfl_xor(s, off, 64);
  if (lane == 0) bp[row] = s + bo[row];
}

// ======================= 256 x BN 8-phase NT GEMM ==========================
// Round-4 verified engine: BM=256, BK=64, 512 thr, 8 phases / 2 K-tiles,
// counted vmcnt (WK0/WK3 keeps, never 0 mid-loop), setprio around MFMA.
// Row-chunk XCD swizzle only (z-pair measured harmful, r4).
// BIAS_MODE: 0 none, 1 bias[col], 3 col<1024?bias:bias2.
// EPI: 0 plain, 1 exp(v)+rowsum->Srow atomics, 2 scale by 1/Srow (pre-bias).
template <int BN, int OUT_F32, int BIAS_MODE, int EPI>
__global__ __launch_bounds__(512, 2) void gemm8p(
    const unsigned short* __restrict__ A, const unsigned short* __restrict__ B,
    void* __restrict__ Cv, const float* __restrict__ bias,
    const float* __restrict__ bias2, float* __restrict__ Srow, int K, int lda,
    int ldb, int ldc, long long bsA, long long bsB, long long bsC,
    float alpha) {
  static_assert(BN == 256 || BN == 128, "BN");
  constexpr int WMW = (BN == 256) ? 2 : 4;  // waves along M
  constexpr int WNW = 8 / WMW;              // waves along N
  constexpr int MF = 8 / WMW;               // M frags per quadrant-phase
  constexpr int NF = 2;                     // N frags per quadrant-phase
  constexpr int NBH = BN / 2;               // B half-tile rows
  constexpr int GB = (BN == 256) ? 2 : 1;   // gloads per B half-tile stage
  constexpr int BSLOT = NBH * 64;           // ushorts per B half-slot
  constexpr int WK0 = (BN == 256) ? 6 : 5;  // p0/p4-end keep
  constexpr int WK3 = (BN == 256) ? 8 : 6;  // p3/p7-end keep
  constexpr int WPR = (BN == 256) ? 4 : 3;  // prologue keep

  __shared__ unsigned short ldsA[4 * 8192];   // [buf*2+half][128x64]
  __shared__ unsigned short ldsB[4 * BSLOT];  // [buf*2+half][NBH x 64]

  const int tid = threadIdx.x;
  const int lane = tid & 63, wid = tid >> 6;
  const int fr = lane & 15, fq = lane >> 4;
  const int wm = wid / WNW, wn = wid % WNW;

  // XCD-aware chunked swizzle on flattened (y,x); all grids have nwg%8==0.
  const int nx = gridDim.x;
  const int nwg = nx * gridDim.y;
  int f = blockIdx.y * nx + blockIdx.x;
  f = (f & 7) * (nwg >> 3) + (f >> 3);
  const int bx = f % nx, by = f / nx;
  const int bz = blockIdx.z;

  const unsigned short* Ag = A + bz * bsA + (long long)by * 256 * lda;
  const unsigned short* Bg = B + bz * bsB + (long long)bx * BN * ldb;
  const int NT = K >> 6;

  // Staging: LDS write is linear (base + lane*16B); the LDS XOR-swizzle
  // (bits[6:4] ^= bits[10:8]) is applied to the GLOBAL source instead
  // (involution; both sides must match - rule 21).
  const int La0 = wid * 1024 + lane * 16;
  const int La1 = 8192 + La0;
  const int Pa0 = La0 ^ ((La0 >> 4) & 0x70);
  const int Pa1 = La1 ^ ((La1 >> 4) & 0x70);
  const int aR0 = Pa0 >> 7, aC0 = (Pa0 & 127) >> 1;
  const int aR1 = Pa1 >> 7, aC1 = (Pa1 & 127) >> 1;

  auto stageA = [&](int tile, int h) {
    if (tile >= NT) return;
    unsigned short* d = &ldsA[(((tile & 1) << 1) | h) * 8192 + wid * 512];
    GLOAD16(Ag + (long long)(h * 128 + aR0) * lda + tile * 64 + aC0, d);
    GLOAD16(Ag + (long long)(h * 128 + aR1) * lda + tile * 64 + aC1, d + 4096);
  };
  auto stageB = [&](int tile, int h) {
    if (tile >= NT) return;
    unsigned short* d = &ldsB[(((tile & 1) << 1) | h) * BSLOT + wid * 512];
    GLOAD16(Bg + (long long)(h * NBH + aR0) * ldb + tile * 64 + aC0, d);
    if (GB == 2)
      GLOAD16(Bg + (long long)(h * NBH + aR1) * ldb + tile * 64 + aC1, d + 4096);
  };

  // Fragment ds_read offsets (swizzled), ushort units.
  int offA[MF][2], offB[NF][2];
#pragma unroll
  for (int i = 0; i < MF; ++i)
#pragma unroll
    for (int s = 0; s < 2; ++s) {
      int b = (wm * (128 / WMW) + i * 16 + fr) * 128 + s * 64 + fq * 16;
      offA[i][s] = (b ^ ((b >> 4) & 0x70)) >> 1;
    }
#pragma unroll
  for (int n = 0; n < NF; ++n)
#pragma unroll
    for (int s = 0; s < 2; ++s) {
      int b = (wn * 32 + n * 16 + fr) * 128 + s * 64 + fq * 16;
      offB[n][s] = (b ^ ((b >> 4) & 0x70)) >> 1;
    }

  f32x4 acc[2][2][MF][NF] = {};

  // Prologue: tile0 fully + tile1-h0; leave tile1-h0 loads in flight.
  stageA(0, 0); stageB(0, 0); stageA(0, 1); stageB(0, 1);
  stageA(1, 0); stageB(1, 0);
  vmwait<WPR>();
  __builtin_amdgcn_s_barrier();

  for (int kt = 0; kt < NT; kt += 2) {
    const bool tail = (kt + 2 >= NT);
#pragma unroll
    for (int t2 = 0; t2 < 2; ++t2) {
      const int buf = (kt + t2) & 1;
#pragma unroll
      for (int ph = 0; ph < 4; ++ph) {
        const int mh = ph >> 1, nh = ph & 1;
        const int p = t2 * 4 + ph;
        short8 av[MF][2], bw[NF][2];
        const unsigned short* pa = &ldsA[((buf << 1) | mh) * 8192];
        const unsigned short* pb = &ldsB[((buf << 1) | nh) * BSLOT];
#pragma unroll
        for (int i = 0; i < MF; ++i)
#pragma unroll
          for (int s = 0; s < 2; ++s)
            av[i][s] = *(const short8*)(pa + offA[i][s]);
#pragma unroll
        for (int n = 0; n < NF; ++n)
#pragma unroll
          for (int s = 0; s < 2; ++s)
            bw[n][s] = *(const short8*)(pb + offB[n][s]);
        // Stage schedule: each slot's overwrite issues one phase after the
        // last read of its previous occupant (WAR safe via the barriers).
        if (p == 0) stageA(kt + 1, 1);
        else if (p == 1) stageB(kt + 1, 1);
        else if (p == 2) stageA(kt + 2, 0);
        else if (p == 3) stageB(kt + 2, 0);
        else if (p == 4) stageA(kt + 2, 1);
        else if (p == 5) stageB(kt + 2, 1);
        else if (p == 6) stageA(kt + 3, 0);
        else stageB(kt + 3, 0);
        __builtin_amdgcn_s_barrier();
        __builtin_amdgcn_s_setprio(1);
#pragma unroll
        for (int i = 0; i < MF; ++i)
#pragma unroll
          for (int n = 0; n < NF; ++n)
#pragma unroll
            for (int s = 0; s < 2; ++s)
              acc[mh][nh][i][n] = __builtin_amdgcn_mfma_f32_16x16x32_bf16(
                  av[i][s], bw[n][s], acc[mh][nh][i][n], 0, 0, 0);
        __builtin_amdgcn_s_setprio(0);
        if (p == 0) vmwait<WK0>();
        else if (p == 3) { if (tail) vmwait<0>(); else vmwait<WK3>(); }
        else if (p == 4) { if (tail) vmwait<0>(); else vmwait<WK0>(); }
        else if (p == 7) vmwait<WK3>();
        __builtin_amdgcn_s_barrier();
      }
    }
  }

  // Epilogue. C/D frag layout: col = 16*frag + fr, row = fq*4 + j.
  const long long cb0 = (long long)bz * bsC;
  float* sredf = (float*)ldsA;  // [256][WNW] row-sum scratch (EPI==1)
#pragma unroll
  for (int mh = 0; mh < 2; ++mh)
#pragma unroll
    for (int i = 0; i < MF; ++i)
#pragma unroll
      for (int j = 0; j < 4; ++j) {
        const int row = mh * 128 + wm * (128 / WMW) + i * 16 + fq * 4 + j;
        float inv = 1.0f;
        if (EPI == 2) inv = 1.0f / Srow[(long long)bz * SEQ + by * 256 + row];
        float rps = 0.0f;
#pragma unroll
        for (int nh = 0; nh < 2; ++nh)
#pragma unroll
          for (int n = 0; n < NF; ++n) {
            const int col = bx * BN + nh * NBH + wn * 32 + n * 16 + fr;
            float v = acc[mh][nh][i][n][j] * alpha;
            if (EPI == 1) { v = __expf(v); rps += v; }
            if (EPI == 2) v *= inv;
            if (BIAS_MODE == 1) v += bias[col];
            if (BIAS_MODE == 3) v += (col < 1024) ? bias[col] : bias2[col - 1024];
            const long long idx =
                cb0 + (long long)(by * 256 + row) * ldc + col;
            if (OUT_F32)
              ((float*)Cv)[idx] = v;
            else
              ((unsigned short*)Cv)[idx] = f2bf(v);
          }
        if (EPI == 1) {
          rps += __shfl_xor(rps, 1, 64);
          rps += __shfl_xor(rps, 2, 64);
          rps += __shfl_xor(rps, 4, 64);
          rps += __shfl_xor(rps, 8, 64);
          if (fr == 0) sredf[row * WNW + wn] = rps;
        }
      }
  if (EPI == 1) {
    __syncthreads();
    if (tid < 256) {
      float s4 = 0.0f;
#pragma unroll
      for (int w = 0; w < WNW; ++w) s4 += sredf[tid * WNW + w];
      atomicAdd(Srow + (long long)bz * SEQ + by * 256 + tid, s4);
    }
  }
}

extern "C" void kernel_launch(void* const* d_in, const int* in_sizes, int n_in,
                              void* d_out, int out_size, void* d_ws,
                              size_t ws_size, hipStream_t stream) {
  (void)in_sizes; (void)n_in; (void)out_size; (void)ws_size;
  const float* x = (const float*)d_in[0];
  const float* Wq = (const float*)d_in[1];
  const float* bq = (const float*)d_in[2];
  const float* Wk = (const float*)d_in[3];
  const float* bk = (const float*)d_in[4];
  const float* Wv = (const float*)d_in[5];
  const float* bv = (const float*)d_in[6];
  const float* Wo = (const float*)d_in[7];
  const float* bo = (const float*)d_in[8];
  float* out = (float*)d_out;

  char* ws = (char*)d_ws;
  unsigned short* xbf  = (unsigned short*)(ws + 0);         // 16 MiB
  unsigned short* wqk  = (unsigned short*)(ws + 16777216);  // 4 MiB [2048][1024]
  unsigned short* wobf = (unsigned short*)(ws + 20971520);  // 2 MiB
  unsigned short* wvT  = (unsigned short*)(ws + 23068672);  // 2 MiB (Wv^T)
  unsigned short* wov  = (unsigned short*)(ws + 25165824);  // 2 MiB (Wo.Wv)
  float*          bpr  = (float*)        (ws + 27262976);   // 4 KiB (Wo.bv+bo)
  float*          Srow = (float*)        (ws + 28311552);   // 32 KiB rowsums
  unsigned short* VWoT = (unsigned short*)(ws + 33554432);  // 16 MiB [1024][8192]
  unsigned short* QKb  = (unsigned short*)(ws + 50331648);  // 32 MiB [8192][2048]
  unsigned short* P    = (unsigned short*)(ws + 83886080);  // 32 MiB [4][2048][2048]

  // casts & small precomputes (round-12 dataflow)
  cast_f32_to_bf16<<<4096, 256, 0, stream>>>(x, xbf, BS * HID);
  cast_f32_to_bf16<<<512, 256, 0, stream>>>(Wq, wqk, HID * HID);
  cast_f32_to_bf16<<<512, 256, 0, stream>>>(Wk, wqk + HID * HID, HID * HID);
  cast_f32_to_bf16<<<512, 256, 0, stream>>>(Wo, wobf, HID * HID);
  transpose_cast<<<dim3(32, 32), 256, 0, stream>>>(Wv, wvT);
  bias_fuse<<<256, 256, 0, stream>>>(Wo, bv, bo, bpr);
  hipMemsetAsync(Srow, 0, NB * SEQ * sizeof(float), stream);

  // wov[h,k] = sum_j Wo[h,j] Wv[j,k] = NT(wobf, wvT) : [1024,1024]
  gemm8p<128, 0, 0, 0><<<dim3(8, 4, 1), 512, 0, stream>>>(
      wobf, wvT, wov, nullptr, nullptr, nullptr, HID, HID, HID, HID, 0, 0, 0,
      1.0f);
  // VWoT[h,s] = sum_k wov[h,k] x[s,k] = NT(wov, xbf) : [1024,8192]
  gemm8p<128, 0, 0, 0><<<dim3(64, 4, 1), 512, 0, stream>>>(
      wov, xbf, VWoT, nullptr, nullptr, nullptr, HID, HID, HID, BS, 0, 0, 0,
      1.0f);
  // [Q|K] = x @ [Wq;Wk]^T + [bq;bk] : [8192,2048]
  gemm8p<256, 0, 3, 0><<<dim3(8, 32, 1), 512, 0, stream>>>(
      xbf, wqk, QKb, bq, bk, nullptr, HID, HID, HID, 2048, 0, 0, 0, 1.0f);
  // P = exp(Q @ K^T / 32) per batch + rowsums : [4][2048][2048]
  gemm8p<256, 0, 0, 1><<<dim3(8, 8, NB), 512, 0, stream>>>(
      QKb, QKb + 1024, P, nullptr, nullptr, Srow, HID, 2048, 2048, SEQ,
      (long long)SEQ * 2048, (long long)SEQ * 2048, (long long)SEQ * SEQ,
      0.03125f);
  // out = (P @ VWoT^T) / Srow + b' : [8192,1024] fp32 (k-window via bsB)
  gemm8p<128, 1, 1, 2><<<dim3(8, 8, NB), 512, 0, stream>>>(
      P, VWoT, out, bpr, nullptr, Srow, SEQ, SEQ, BS, HID,
      (long long)SEQ * SEQ, (long long)SEQ, (long long)SEQ * HID, 1.0f);
}